// Round 9
// baseline (288.411 us; speedup 1.0000x reference)
//
#include <hip/hip_runtime.h>
#include <cstdint>

// Problem constants (B,S,H,D from reference)
#define BB 4
#define SS 2048
#define HH 8
#define DD 64
#define CC 64          // chunk length
#define NCK (SS/CC)    // 32 chunks
#define BHH (BB*HH)    // 32

typedef __attribute__((ext_vector_type(8))) short  short8;   // 8 bf16 (MFMA A/B frag)
typedef __attribute__((ext_vector_type(4))) float  f32x4;    // MFMA C/D frag
typedef __attribute__((ext_vector_type(4))) unsigned short us4;
typedef unsigned long long u64;

__device__ __forceinline__ float elu1(float x) {
    return x > 0.f ? x + 1.f : __expf(x);
}
// fp32 -> bf16 RNE
__device__ __forceinline__ unsigned short f2bf(float f) {
    unsigned int u = __float_as_uint(f);
    u += 0x7FFFu + ((u >> 16) & 1u);
    return (unsigned short)(u >> 16);
}
__device__ __forceinline__ float bf2f(unsigned short h) {
    return __uint_as_float(((unsigned int)h) << 16);
}
// XOR swizzle for [64][64] bf16 tiles (rows 128B). ws tiles store the exact
// swizzled LDS byte image (element-wise ops are layout-agnostic).
#define SWZ(r,c) ((r) * DD + ((c) ^ (((r) & 7) << 3)))

// 4x4 lane-transpose across lane groups M0,M1 (4 shfl_xor).
template<int M0, int M1>
__device__ __forceinline__ void xpose4(float v[4], int lane) {
    {
        const bool hi = (lane & M0) != 0;
        float x0 = hi ? v[0] : v[1];
        float x1 = hi ? v[2] : v[3];
        float r0 = __shfl_xor(x0, M0);
        float r1 = __shfl_xor(x1, M0);
        if (hi) { v[0] = r0; v[2] = r1; } else { v[1] = r0; v[3] = r1; }
    }
    {
        const bool hi = (lane & M1) != 0;
        float x0 = hi ? v[0] : v[2];
        float x1 = hi ? v[1] : v[3];
        float r0 = __shfl_xor(x0, M1);
        float r1 = __shfl_xor(x1, M1);
        if (hi) { v[0] = r0; v[1] = r1; } else { v[2] = r0; v[3] = r1; }
    }
}

__device__ __forceinline__ u64 pack4bf(const float v[4]) {
    u64 r;
    r  = (u64)f2bf(v[0]);
    r |= (u64)f2bf(v[1]) << 16;
    r |= (u64)f2bf(v[2]) << 32;
    r |= (u64)f2bf(v[3]) << 48;
    return r;
}

// ---------------------------------------------------------------------------
// Kernel 1: per-chunk state + fused "last block per bh does the prefix".
//  - stage k (elu*scale), v; K^T/V^T swizzled bf16 LDS tiles (4x4 lane xpose)
//  - MFMA S_c^T[t][d] = sum_s vT[t,s]*kT[d,s]; write V^T image + S_c image
//  - threadfence + device-scope counter; the 32nd arrival for its bh scans
//    the 32 images in-place to EXCLUSIVE fp32 prefixes (L2/L3-hot reads,
//    no spin: all other blocks exit immediately).
// grid = 1024, 256 thr, LDS 16 KB.
// ---------------------------------------------------------------------------
__global__ __launch_bounds__(256) void state_kernel(
    const float* __restrict__ qk, const float* __restrict__ v,
    unsigned short* __restrict__ vtws, u64* __restrict__ Sws,
    int* __restrict__ flags)
{
    const int blk = blockIdx.x;
    const int bh = blk / NCK, c = blk % NCK;
    const int b = bh / HH, h = bh % HH;
    const int s0 = c * CC;

    __shared__ __align__(16) unsigned short kT[CC * DD];   // K^T [d][s] swz
    __shared__ __align__(16) unsigned short vT[CC * DD];   // V^T [t][s] swz
    __shared__ int isLast;

    const int tid = threadIdx.x, lane = tid & 63;

#pragma unroll
    for (int iter = 0; iter < 4; ++iter) {
        const int it = iter * 256 + tid;
        const int r = it >> 4, c0 = (it & 15) * 4;   // row s=r, cols c0..c0+3
        const int g = lane >> 4;                     // row within 4x4 block
        const int rb = r - g;                        // 4-aligned block row base

        const size_t krow = (((size_t)(b * SS + s0 + r) * 2 + 1) * HH + h) * DD;
        float4 fk = *reinterpret_cast<const float4*>(qk + krow + c0);
        float kv4[4] = { elu1(fk.x) * 0.125f, elu1(fk.y) * 0.125f,
                         elu1(fk.z) * 0.125f, elu1(fk.w) * 0.125f };
        xpose4<16, 32>(kv4, lane);                   // -> col d=c0+g, rows rb..rb+3
        *reinterpret_cast<u64*>(&kT[SWZ(c0 + g, rb)]) = pack4bf(kv4);

        float4 fv = *reinterpret_cast<const float4*>(
            v + ((size_t)(b * SS + s0 + r) * HH + h) * DD + c0);
        float vv4[4] = { fv.x, fv.y, fv.z, fv.w };
        xpose4<16, 32>(vv4, lane);
        *reinterpret_cast<u64*>(&vT[SWZ(c0 + g, rb)]) = pack4bf(vv4);
    }
    __syncthreads();

    // dump V^T byte image (linear read of swizzled LDS -> ws stays swizzled)
#pragma unroll
    for (int j = 0; j < 2; ++j) {
        const int slot = j * 256 + tid;
        *reinterpret_cast<short8*>(vtws + (size_t)blk * 4096 + slot * 8) =
            *reinterpret_cast<const short8*>(&vT[slot * 8]);
    }

    // MFMA: S_c^T[t][d] = sum_s vT[t,s] * kT[d,s]
    const int lr = lane & 15, lk = (lane >> 4) * 8;
    const int wid = tid >> 6, mbase = wid * 16;
    f32x4 sc[4] = {};
#pragma unroll
    for (int kk = 0; kk < 2; ++kk) {
        short8 a = *reinterpret_cast<const short8*>(&vT[SWZ(mbase + lr, kk * 32 + lk)]);
#pragma unroll
        for (int nb = 0; nb < 4; ++nb) {
            short8 bk = *reinterpret_cast<const short8*>(&kT[SWZ(nb * 16 + lr, kk * 32 + lk)]);
            sc[nb] = __builtin_amdgcn_mfma_f32_16x16x32_bf16(a, bk, sc[nb], 0, 0, 0);
        }
    }
    // S_c image write (swizzled [t][d] u64 image)
    const int crow = (lane >> 4) * 4;
#pragma unroll
    for (int nb = 0; nb < 4; ++nb) {
        float cv[4] = { sc[nb][0], sc[nb][1], sc[nb][2], sc[nb][3] };
        xpose4<1, 2>(cv, lane);                      // lane: row t=crow+(lane&3), 4 d-cols
        const int t  = mbase + crow + (lane & 3);
        const int d0 = nb * 16 + (lr & ~3);
        Sws[(size_t)blk * 1024 + (SWZ(t, d0) >> 2)] = pack4bf(cv);
    }

    // ---- publish + elect the last block of this bh ----
    __threadfence();                 // device-scope release of the image stores
    __syncthreads();
    if (tid == 0) {
        int old = __hip_atomic_fetch_add(&flags[bh], 1,
                                         __ATOMIC_ACQ_REL, __HIP_MEMORY_SCOPE_AGENT);
        isLast = (old == NCK - 1);
    }
    __syncthreads();
    if (!isLast) return;
    __threadfence();                 // acquire: invalidate stale lines before reads

    // ---- in-place exclusive prefix scan of this bh's 32 images ----
    u64* base = Sws + (size_t)bh * NCK * 1024 + (size_t)tid * 4;
    float run[16] = {};
    for (int j = 0; j < NCK; ++j) {
        u64* p = base + (size_t)j * 1024;
        u64 x[4];
#pragma unroll
        for (int w2 = 0; w2 < 4; ++w2) x[w2] = p[w2];
#pragma unroll
        for (int w2 = 0; w2 < 4; ++w2) {
            float cv[4] = { run[w2 * 4 + 0], run[w2 * 4 + 1],
                            run[w2 * 4 + 2], run[w2 * 4 + 3] };
            p[w2] = pack4bf(cv);     // exclusive
        }
#pragma unroll
        for (int w2 = 0; w2 < 4; ++w2) {
            run[w2 * 4 + 0] += bf2f((unsigned short)(x[w2]));
            run[w2 * 4 + 1] += bf2f((unsigned short)(x[w2] >> 16));
            run[w2 * 4 + 2] += bf2f((unsigned short)(x[w2] >> 32));
            run[w2 * 4 + 3] += bf2f((unsigned short)(x[w2] >> 48));
        }
    }
}

// ---------------------------------------------------------------------------
// Kernel 2: out[s][t] = norm(s) * ( Q@S_excl + causal(Q K^T)@V )
// S_excl/V^T staged via global_load_lds (verbatim byte images, async);
// q,k staged from fp32 with elu (VALU work overlaps the async loads).
// grid = 1024, 256 thr, LDS 32 KB.
// ---------------------------------------------------------------------------
__global__ __launch_bounds__(256, 4) void out_kernel(
    const float* __restrict__ qk, const float* __restrict__ nrm,
    const float* __restrict__ offset,
    const unsigned short* __restrict__ vtws, const u64* __restrict__ Sws,
    float* __restrict__ out)
{
    const int blk = blockIdx.x;
    const int bh = blk / NCK, c = blk % NCK;
    const int b = bh / HH, h = bh % HH;
    const int s0 = c * CC;

    __shared__ __align__(16) unsigned short qb[CC * DD];   // Q  [s][d]  swz
    __shared__ __align__(16) unsigned short kb[CC * DD];   // K  [s2][d] swz -> As[s][s2]
    __shared__ __align__(16) unsigned short vT[CC * DD];   // V^T[t][s]  swz
    __shared__ __align__(16) unsigned short stk[CC * DD];  // S_excl^T[t][d] swz

    const int tid = threadIdx.x, lane = tid & 63;
    const int wid = tid >> 6;

    // ---- async stage S_excl, V^T images (no VGPR round trip) ----
    {
        const unsigned short* gS = (const unsigned short*)(Sws + (size_t)blk * 1024);
        const unsigned short* gV = vtws + (size_t)blk * 4096;
#pragma unroll
        for (int j = 0; j < 2; ++j) {
            const unsigned short* gp1 = gS + (size_t)(j * 256 + tid) * 8;
            __builtin_amdgcn_global_load_lds(
                (const __attribute__((address_space(1))) void*)gp1,
                (__attribute__((address_space(3))) void*)(stk + j * 2048 + wid * 512),
                16, 0, 0);
            const unsigned short* gp2 = gV + (size_t)(j * 256 + tid) * 8;
            __builtin_amdgcn_global_load_lds(
                (const __attribute__((address_space(1))) void*)gp2,
                (__attribute__((address_space(3))) void*)(vT + j * 2048 + wid * 512),
                16, 0, 0);
        }
    }

    // ---- stage q,k (fp32 -> elu1 -> bf16, swizzled) under the async loads ----
#pragma unroll
    for (int iter = 0; iter < 4; ++iter) {
        const int it = iter * 256 + tid;
        const int r = it >> 4, c0 = (it & 15) * 4;
        const size_t qrow = (((size_t)(b * SS + s0 + r) * 2 + 0) * HH + h) * DD;

        float4 fq = *reinterpret_cast<const float4*>(qk + qrow + c0);
        us4 uq; uq.x = f2bf(elu1(fq.x)); uq.y = f2bf(elu1(fq.y));
                uq.z = f2bf(elu1(fq.z)); uq.w = f2bf(elu1(fq.w));
        *reinterpret_cast<us4*>(&qb[SWZ(r, c0)]) = uq;

        float4 fk = *reinterpret_cast<const float4*>(qk + qrow + (size_t)HH * DD + c0);
        us4 uk; uk.x = f2bf(elu1(fk.x) * 0.125f); uk.y = f2bf(elu1(fk.y) * 0.125f);
                uk.z = f2bf(elu1(fk.z) * 0.125f); uk.w = f2bf(elu1(fk.w) * 0.125f);
        *reinterpret_cast<us4*>(&kb[SWZ(r, c0)]) = uk;
    }

    const int lr    = lane & 15;
    const int lk    = (lane >> 4) * 8;
    const int mbase = wid * 16;
    const int crow  = (lane >> 4) * 4;

    // epilogue norm inputs (issue loads early)
    const float off = offset[h];
    float nv[4];
#pragma unroll
    for (int r = 0; r < 4; ++r) {
        const int s = s0 + mbase + crow + r;
        nv[r] = nrm[(size_t)(b * SS + s) * HH + h] + off;
    }

    __syncthreads();   // drains gload_lds (vmcnt) + ds writes

    // ---- phase 1: O = Q@S_excl ; scores = Q K^T ----
    f32x4 acc[4] = {};
    f32x4 as4[4] = {};
#pragma unroll
    for (int kk = 0; kk < 2; ++kk) {
        short8 aq = *reinterpret_cast<const short8*>(&qb[SWZ(mbase + lr, kk * 32 + lk)]);
#pragma unroll
        for (int nb = 0; nb < 4; ++nb) {
            short8 bs = *reinterpret_cast<const short8*>(&stk[SWZ(nb * 16 + lr, kk * 32 + lk)]);
            acc[nb] = __builtin_amdgcn_mfma_f32_16x16x32_bf16(aq, bs, acc[nb], 0, 0, 0);
            short8 bk = *reinterpret_cast<const short8*>(&kb[SWZ(nb * 16 + lr, kk * 32 + lk)]);
            as4[nb] = __builtin_amdgcn_mfma_f32_16x16x32_bf16(aq, bk, as4[nb], 0, 0, 0);
        }
    }
    __syncthreads();   // all waves done reading kb before overlay

    // ---- causal-masked scores into kb as As[s][s2] (wave-local rows) ----
#pragma unroll
    for (int nb = 0; nb < 4; ++nb) {
#pragma unroll
        for (int r = 0; r < 4; ++r) {
            const int s_loc = mbase + crow + r;
            const int s2    = nb * 16 + lr;
            const float val = (s2 <= s_loc) ? as4[nb][r] : 0.f;
            kb[SWZ(s_loc, s2)] = f2bf(val);
        }
    }
    // reads below are same-wave rows; compiler inserts lgkmcnt ordering

    // ---- phase 2: O += As @ V ----
#pragma unroll
    for (int kk = 0; kk < 2; ++kk) {
        short8 aa = *reinterpret_cast<const short8*>(&kb[SWZ(mbase + lr, kk * 32 + lk)]);
#pragma unroll
        for (int nb = 0; nb < 4; ++nb) {
            short8 bv = *reinterpret_cast<const short8*>(&vT[SWZ(nb * 16 + lr, kk * 32 + lk)]);
            acc[nb] = __builtin_amdgcn_mfma_f32_16x16x32_bf16(aa, bv, acc[nb], 0, 0, 0);
        }
    }

    // ---- epilogue ----
#pragma unroll
    for (int r = 0; r < 4; ++r) nv[r] = 1.f / (1.f + __expf(nv[r]));
#pragma unroll
    for (int nb = 0; nb < 4; ++nb) {
#pragma unroll
        for (int r = 0; r < 4; ++r) {
            const int s = s0 + mbase + crow + r;
            out[((size_t)(b * SS + s) * HH + h) * DD + nb * 16 + lr] = acc[nb][r] * nv[r];
        }
    }
}

// ---------------------------------------------------------------------------
extern "C" void kernel_launch(void* const* d_in, const int* in_sizes, int n_in,
                              void* d_out, int out_size, void* d_ws, size_t ws_size,
                              hipStream_t stream) {
    const float* qk     = (const float*)d_in[0];
    const float* v      = (const float*)d_in[1];
    const float* nrm    = (const float*)d_in[2];
    const float* offset = (const float*)d_in[3];
    float* out = (float*)d_out;

    const size_t TILE = (size_t)BHH * NCK * 4096;    // bf16 elems per buffer
    unsigned short* vtws = (unsigned short*)d_ws;    // 8.39 MB
    u64* Sws = (u64*)(vtws + TILE);                  // 8.39 MB (u64 image)
    int* flags = (int*)(Sws + (size_t)BHH * NCK * 1024);

    hipMemsetAsync(flags, 0, BHH * sizeof(int), stream);   // ws is poisoned 0xAA
    state_kernel<<<dim3(BHH * NCK), dim3(256), 0, stream>>>(qk, v, vtws, Sws, flags);
    out_kernel<<<dim3(BHH * NCK), dim3(256), 0, stream>>>(qk, nrm, offset, vtws, Sws, out);
}